// Round 7
// baseline (251.443 us; speedup 1.0000x reference)
//
#include <hip/hip_runtime.h>

#define NN 30000
#define NE 480000
#define NG 512
#define MAXD 48
#define BATCH 32
#define NB 938    // ceil(30000/32)
#define HPAD 144  // h_s row stride in shorts
#define XTS 272   // [x|h] tile row stride in shorts (tail GEMM)

// k_prep block ranges
#define PREP_EDGE 1875  // edge boundary detection
#define PREP_WCVT 48    // W_hh (32) + W_out (16) fragment pre-conversion
#define PREP_PROJ 469   // proj GEMM blocks (inline W_ih conversion)

typedef __attribute__((ext_vector_type(8))) short short8;
typedef __attribute__((ext_vector_type(4))) short s16x4;
typedef __attribute__((ext_vector_type(4))) float f32x4;
typedef __attribute__((ext_vector_type(4))) int i32x4;

#define L2E 1.44269504089f   // log2(e)
#define L2E2 2.88539008178f  // 2*log2(e)

static __device__ __forceinline__ short f2bs(float f) {
  unsigned u = __builtin_bit_cast(unsigned, f);
  u = (u + 0x7fffu + ((u >> 16) & 1u)) >> 16;
  return (short)u;
}
// packed f32->bf16 (RNE, same rounding as f2bs): lo = S0, hi = S1.
// Plain-VALU inline asm is safe (hw-interlocked); only MFMA asm was not (r1).
static __device__ __forceinline__ unsigned cvtpk(float lo, float hi) {
  unsigned r;
  asm("v_cvt_pk_bf16_f32 %0, %1, %2" : "=v"(r) : "v"(lo), "v"(hi));
  return r;
}
// async 16B-per-lane gather into LDS: dest = ldsbase + lane*16
static __device__ __forceinline__ void gl_lds16(const short* g, short* l) {
  __builtin_amdgcn_global_load_lds(
      (const __attribute__((address_space(1))) void*)g,
      (__attribute__((address_space(3))) void*)l, 16, 0, 0);
}

// Pin a bf16x8 MFMA B-fragment to AGPRs (gfx950 unified RF: MFMA reads A/B
// from AGPR). Round-3 rocprof verified this kills the arch-VGPR spill:
// k_lstm WRITE_SIZE 107,866 KB -> 7,500 KB. Keep the builtin MFMA
// (compiler-managed hazards); full inline-asm MFMA broke the hazard
// recognizer in round 1 (absmax 0.47).
#define PIN_AGPR(w_) asm("" : "+a"(w_))

// ---- k_prep: three independent jobs in one grid (block-range dispatch) so
// proj overlaps the edge pass instead of serializing behind it:
//  [0,1875)    edge boundary detection (src sorted)
//  [1875,1923) one-time W_hh/W_out bf16 fragment pre-conversion (exp2-domain
//              scale on W_hh rows: gates i,f,o by log2e, g by 2*log2e)
//  [1923,2392) proj = X @ W_ih.T + (b_ih+b_hh), bf16 MFMA, permuted+scaled;
//              W_ih converted inline per block (r0-r3 pattern; cheap)
// ----
__global__ __launch_bounds__(256)
__attribute__((amdgpu_waves_per_eu(2, 2))) void k_prep(
    const int* __restrict__ src, int* __restrict__ starts, int* __restrict__ ends,
    const float* __restrict__ W_ih, const float* __restrict__ W_hh,
    const float* __restrict__ Wout, short* __restrict__ whh_s,
    short* __restrict__ wout_s, const float* __restrict__ x,
    const float* __restrict__ b_ih, const float* __restrict__ b_hh,
    short* __restrict__ proj) {
  __shared__ __align__(16) short xs[64 * HPAD];  // proj path only
  const int b = blockIdx.x, tid = threadIdx.x;

  if (b < PREP_EDGE) {  // ---- edges ----
    int e = b * 256 + tid;
    if (e >= NE) return;
    int s = src[e];
    if (e == 0 || src[e - 1] != s) starts[s] = e;
    if (e == NE - 1 || src[e + 1] != s) ends[s] = e + 1;
    return;
  }

  const int wv = tid >> 6, lane = tid & 63, lq = lane >> 4, lc = lane & 15;

  if (b < PREP_EDGE + PREP_WCVT) {  // ---- wcvt: W_hh + W_out ----
    const int f = b - PREP_EDGE;  // 0..47
    if (f < 32) {
      const int g = f >> 3, db = (f >> 2) & 1, kt = f & 3;
      const float s = (g == 2) ? L2E2 : L2E;
      const float* p =
          &W_hh[(g * 128 + wv * 32 + db * 16 + lc) * 128 + kt * 32 + lq * 8];
      f32x4 a = *(const f32x4*)p;
      f32x4 c = *(const f32x4*)(p + 4);
      short8 w;
      w[0] = f2bs(a[0] * s); w[1] = f2bs(a[1] * s); w[2] = f2bs(a[2] * s); w[3] = f2bs(a[3] * s);
      w[4] = f2bs(c[0] * s); w[5] = f2bs(c[1] * s); w[6] = f2bs(c[2] * s); w[7] = f2bs(c[3] * s);
      *(short8*)&whh_s[(f * 256 + tid) * 8] = w;
    } else {
      const int fo = f - 32;  // 0..15 (W_out: NOT scaled)
      const int db = fo >> 3, kt = fo & 7;
      short8 w;
#pragma unroll
      for (int jj = 0; jj < 8; ++jj)
        w[jj] = f2bs(Wout[(kt * 32 + lq * 8 + jj) * 128 + wv * 32 + db * 16 + lc]);
      *(short8*)&wout_s[(fo * 256 + tid) * 8] = w;
    }
    return;
  }

  // ---- proj ----
  const int base = (b - (PREP_EDGE + PREP_WCVT)) * 64;
  for (int idx4 = tid; idx4 < 64 * 32; idx4 += 256) {
    int row = idx4 >> 5, k4 = (idx4 & 31) << 2;
    f32x4 v = (f32x4){0.f, 0.f, 0.f, 0.f};
    if (base + row < NN) v = *(const f32x4*)&x[(base + row) * 128 + k4];
    int* xr = (int*)&xs[row * HPAD];
    xr[(k4 >> 1)] = (int)cvtpk(v[0], v[1]);
    xr[(k4 >> 1) + 1] = (int)cvtpk(v[2], v[3]);
  }
  short8 wfrag[4][2][4];
#pragma unroll
  for (int g = 0; g < 4; ++g)
#pragma unroll
    for (int db = 0; db < 2; ++db)
#pragma unroll
      for (int kt = 0; kt < 4; ++kt) {
        const float s = (g == 2) ? L2E2 : L2E;
        const float* p =
            &W_ih[(g * 128 + wv * 32 + db * 16 + lc) * 128 + kt * 32 + lq * 8];
        f32x4 a = *(const f32x4*)p;
        f32x4 c = *(const f32x4*)(p + 4);
        short8 w;
        w[0] = f2bs(a[0] * s); w[1] = f2bs(a[1] * s); w[2] = f2bs(a[2] * s); w[3] = f2bs(a[3] * s);
        w[4] = f2bs(c[0] * s); w[5] = f2bs(c[1] * s); w[6] = f2bs(c[2] * s); w[7] = f2bs(c[3] * s);
        PIN_AGPR(w);
        wfrag[g][db][kt] = w;
      }
  float bias_v[4][2];
#pragma unroll
  for (int g = 0; g < 4; ++g)
#pragma unroll
    for (int db = 0; db < 2; ++db) {
      int j = g * 128 + wv * 32 + db * 16 + lc;
      bias_v[g][db] = (b_ih[j] + b_hh[j]) * ((g == 2) ? L2E2 : L2E);
    }
  __syncthreads();

#pragma unroll
  for (int mt = 0; mt < 4; ++mt) {
    short8 afrag[4];
#pragma unroll
    for (int kt = 0; kt < 4; ++kt)
      afrag[kt] = *(const short8*)&xs[(mt * 16 + lc) * HPAD + kt * 32 + lq * 8];
    f32x4 acc[4][2];
#pragma unroll
    for (int g = 0; g < 4; ++g)
#pragma unroll
      for (int db = 0; db < 2; ++db) {
        float bb = bias_v[g][db];
        acc[g][db] = (f32x4){bb, bb, bb, bb};
#pragma unroll
        for (int kt = 0; kt < 4; ++kt)
          acc[g][db] = __builtin_amdgcn_mfma_f32_16x16x32_bf16(
              afrag[kt], wfrag[g][db][kt], acc[g][db], 0, 0, 0);
      }
#pragma unroll
    for (int r = 0; r < 4; ++r) {
      int row = base + mt * 16 + lq * 4 + r;
      if (row < NN) {
        i32x4 w;
        w[0] = (int)cvtpk(acc[0][0][r], acc[0][1][r]);
        w[1] = (int)cvtpk(acc[1][0][r], acc[1][1][r]);
        w[2] = (int)cvtpk(acc[2][0][r], acc[2][1][r]);
        w[3] = (int)cvtpk(acc[3][0][r], acc[3][1][r]);
        *(i32x4*)&proj[row * NG + (wv * 16 + lc) * 8] = w;
      }
    }
  }
}

// ---- degree histogram (118 blocks; ghist zeroed by launch-side memset) ----
__global__ void k_hist(const int* __restrict__ starts, const int* __restrict__ ends,
                       int* __restrict__ ghist) {
  __shared__ int h[MAXD + 1];
  const int tid = threadIdx.x;
  if (tid <= MAXD) h[tid] = 0;
  __syncthreads();
  int n = blockIdx.x * 256 + tid;
  if (n < NN) {
    int c = ends[n] - starts[n]; c = c > MAXD ? MAXD : c;
    atomicAdd(&h[c], 1);
  }
  __syncthreads();
  if (tid <= MAXD && h[tid] > 0) atomicAdd(&ghist[tid], h[tid]);
}

// ---- scatter with inline descending-bucket scan; gclaim[] zeroed by the
// launch-side memset. Within-bucket order arbitrary. ----
__global__ void k_scat2(const int* __restrict__ starts, const int* __restrict__ ends,
                        const int* __restrict__ ghist, int* __restrict__ gclaim,
                        int* __restrict__ order) {
  __shared__ int lh[MAXD + 1];
  __shared__ int lbase[MAXD + 1];
  __shared__ int sbase[MAXD + 1];
  const int tid = threadIdx.x;
  if (tid <= MAXD) lh[tid] = 0;
  __syncthreads();
  int n = blockIdx.x * 256 + tid;
  int c = 0, rank = 0;
  if (n < NN) {
    c = ends[n] - starts[n]; c = c > MAXD ? MAXD : c;
    rank = atomicAdd(&lh[c], 1);
  }
  if (tid == 0) {
    int tot = 0;
    for (int b = MAXD; b >= 0; --b) { sbase[b] = tot; tot += ghist[b]; }
  }
  __syncthreads();
  if (tid <= MAXD && lh[tid] > 0)
    lbase[tid] = sbase[tid] + atomicAdd(&gclaim[tid], lh[tid]);
  __syncthreads();
  if (n < NN) order[lbase[c] + rank] = n;
}

// ---- LSTM + fused output GEMM. Inner loop unchanged since r5 (W_hh
// AGPR-pinned, exp2-domain gates, distance-1 gl_lds prefetch, one barrier
// per step). r7: neighbor ids gathered DIRECTLY from etrg (nbr[n*MAXD+p]
// was by construction etrg[starts[n]+p]) — kills the k_nbr materialization
// pass and its 11.5 MB round-trip. Tail GEMM (r6) kept: [x|h] staged into
// dead pbuf, W_out frags in the dead wfrag AGPR space. ----
__global__ __launch_bounds__(256)
__attribute__((amdgpu_waves_per_eu(2, 2))) void k_lstm(
    const short* __restrict__ whh_s, const short* __restrict__ proj,
    const int* __restrict__ order, const int* __restrict__ starts,
    const int* __restrict__ ends, const int* __restrict__ etrg,
    const short* __restrict__ wout_s, const float* __restrict__ x,
    float* __restrict__ out) {
  __shared__ __align__(16) short h_s[2][BATCH * HPAD];   // 18432 B
  __shared__ __align__(16) short pbuf[4][8][64 * 8];     // 32768 B, wave-private slots
  __shared__ unsigned short nbr_s[BATCH][MAXD];          // 3072 B
  __shared__ int nodes_s[BATCH];
  __shared__ int cnts_s[BATCH];
  __shared__ int starts_s[BATCH];

  const int tid = threadIdx.x;
  const int wv = tid >> 6, lane = tid & 63, lq = lane >> 4, lc = lane & 15;

  const short8* whhv = (const short8*)whh_s;
  short8 wfrag[4][2][4];
#pragma unroll
  for (int g = 0; g < 4; ++g)
#pragma unroll
    for (int db = 0; db < 2; ++db)
#pragma unroll
      for (int kt = 0; kt < 4; ++kt) {
        short8 w = whhv[(g * 8 + db * 4 + kt) * 256 + tid];
        PIN_AGPR(w);
        wfrag[g][db][kt] = w;
      }

  const int batch = blockIdx.x;
  if (tid < BATCH) {
    int gidx = batch * BATCH + tid;
    int node = 0, c = 0, st = 0;
    if (gidx < NN) {
      node = order[gidx];
      st = starts[node];
      c = ends[node] - st; c = c > MAXD ? MAXD : c;
    }
    nodes_s[tid] = node;
    cnts_s[tid] = c;
    starts_s[tid] = st;
  }
  __syncthreads();
  for (int idx = tid; idx < BATCH * HPAD / 2; idx += 256)
    ((int*)h_s[0])[idx] = 0;
  for (int idx = tid; idx < BATCH * MAXD; idx += 256) {
    int m = idx / MAXD, p = idx - m * MAXD;
    nbr_s[m][p] =
        (p < cnts_s[m]) ? (unsigned short)etrg[starts_s[m] + p] : (unsigned short)0;
  }
  __syncthreads();
  const int T = cnts_s[0];  // descending-bucket grouping -> batch max

  // counts packed 4-per-int (each <= 48 fits in 8 bits)
  int cp[2];
#pragma unroll
  for (int mt = 0; mt < 2; ++mt) {
    int p = 0;
#pragma unroll
    for (int r = 0; r < 4; ++r) p |= cnts_s[mt * 16 + lq * 4 + r] << (r * 8);
    cp[mt] = p;
  }

  float c_v[2][2][4];
  s16x4 hvp[2][2];  // last-written h (bf16) for copy-forward of frozen rows
#pragma unroll
  for (int mt = 0; mt < 2; ++mt)
#pragma unroll
    for (int db = 0; db < 2; ++db) {
#pragma unroll
      for (int r = 0; r < 4; ++r) c_v[mt][db][r] = 0.0f;
      hvp[mt][db] = (s16x4){0, 0, 0, 0};
    }

  const int pcol = (wv * 16 + lc) * 8;
  if (T > 0) {  // prologue: async-gather t=0 slices into pbuf
#pragma unroll
    for (int mt = 0; mt < 2; ++mt)
#pragma unroll
      for (int r = 0; r < 4; ++r) {
        int m = mt * 16 + lq * 4 + r;
        int nb_i = (0 < ((cp[mt] >> (r * 8)) & 255)) ? (int)nbr_s[m][0] : 0;
        gl_lds16(&proj[nb_i * NG + pcol], &pbuf[wv][mt * 4 + r][0]);
      }
  }

  for (int t = 0; t < T; ++t) {
    __syncthreads();  // drains prefetch (vmcnt) + makes h writes visible
    const short* hb = h_s[t & 1];
    short* hw = h_s[(t + 1) & 1];
    const int tn = t + 1;
    const int ts = tn < MAXD ? tn : 0;
#pragma unroll
    for (int mt = 0; mt < 2; ++mt) {
      // consume this step's gathered slices (wave-private slots)
      i32x4 pvi[4];
#pragma unroll
      for (int r = 0; r < 4; ++r)
        pvi[r] = *(const i32x4*)&pbuf[wv][mt * 4 + r][lane * 8];
      f32x4 acc[4][2];
#pragma unroll
      for (int g = 0; g < 4; ++g)
#pragma unroll
        for (int r = 0; r < 4; ++r) {
          unsigned u = (unsigned)pvi[r][g];  // two bf16: db0=lo, db1=hi
          acc[g][0][r] = __builtin_bit_cast(float, u << 16);
          acc[g][1][r] = __builtin_bit_cast(float, u & 0xffff0000u);
        }
      __builtin_amdgcn_sched_barrier(0);  // pvi fully consumed before overwrite
      if (tn < T) {  // prefetch t+1 into the same (now free) slots
#pragma unroll
        for (int r = 0; r < 4; ++r) {
          int m = mt * 16 + lq * 4 + r;
          int nb_i = (tn < ((cp[mt] >> (r * 8)) & 255)) ? (int)nbr_s[m][ts] : 0;
          gl_lds16(&proj[nb_i * NG + pcol], &pbuf[wv][mt * 4 + r][0]);
        }
      }
      __builtin_amdgcn_sched_barrier(0);  // keep prefetch issue early
      short8 afrag[4];
#pragma unroll
      for (int kt = 0; kt < 4; ++kt)
        afrag[kt] = *(const short8*)&hb[(mt * 16 + lc) * HPAD + kt * 32 + lq * 8];
#pragma unroll
      for (int g = 0; g < 4; ++g)
#pragma unroll
        for (int db = 0; db < 2; ++db)
#pragma unroll
          for (int kt = 0; kt < 4; ++kt)
            acc[g][db] = __builtin_amdgcn_mfma_f32_16x16x32_bf16(
                afrag[kt], wfrag[g][db][kt], acc[g][db], 0, 0, 0);
#pragma unroll
      for (int db = 0; db < 2; ++db)
#pragma unroll
        for (int r = 0; r < 4; ++r) {
          float Ei = __builtin_amdgcn_exp2f(-acc[0][db][r]);
          float Eg = __builtin_amdgcn_exp2f(fminf(acc[2][db][r], 125.f));
          float ig = (Eg - 1.f) *
                     __builtin_amdgcn_rcpf((1.f + Ei) * (1.f + Eg));
          float fv = __builtin_amdgcn_rcpf(
              1.f + __builtin_amdgcn_exp2f(-acc[1][db][r]));
          float c2 = fv * c_v[mt][db][r] + ig;
          float Eo = __builtin_amdgcn_exp2f(-acc[3][db][r]);
          float Ec = __builtin_amdgcn_exp2f(fminf(c2 * L2E2, 125.f));
          float h2 = (Ec - 1.f) *
                     __builtin_amdgcn_rcpf((1.f + Eo) * (1.f + Ec));
          if (t < ((cp[mt] >> (r * 8)) & 255)) {
            c_v[mt][db][r] = c2;
            hvp[mt][db][r] = f2bs(h2);
          }
        }
      // unconditional write of (new or carried) h into the other buffer
#pragma unroll
      for (int db = 0; db < 2; ++db)
#pragma unroll
        for (int r = 0; r < 4; ++r)
          hw[(mt * 16 + lq * 4 + r) * HPAD + wv * 32 + db * 16 + lc] =
              hvp[mt][db][r];
    }
  }
  __syncthreads();  // last step's h writes visible; pbuf prefetches drained

  // ---- fused output GEMM: out[32 rows] = [x|h] @ W_out ----
  const short* hf = h_s[T & 1];
  short* xt = (short*)pbuf;  // 32 x XTS(272) shorts = 17408 B, reuses pbuf
  // h half: copy 32x128 bf16 as ints (HPAD-strided -> XTS-strided)
  for (int idx = tid; idx < BATCH * 64; idx += 256) {
    int m = idx >> 6, d2 = idx & 63;
    ((int*)xt)[m * (XTS / 2) + 64 + d2] = ((const int*)&hf[m * HPAD])[d2];
  }
  // x half: gather rows by node id, convert f32->bf16 (cvt_pk)
  for (int idx4 = tid; idx4 < BATCH * 32; idx4 += 256) {
    int m = idx4 >> 5, k4 = (idx4 & 31) << 2;
    f32x4 v = *(const f32x4*)&x[nodes_s[m] * 128 + k4];
    int* xr = (int*)xt + m * (XTS / 2);
    xr[(k4 >> 1)] = (int)cvtpk(v[0], v[1]);
    xr[(k4 >> 1) + 1] = (int)cvtpk(v[2], v[3]);
  }
  // W_out frags into the dead wfrag AGPR space
  const short8* wov = (const short8*)wout_s;
  short8 wf[2][8];
#pragma unroll
  for (int db = 0; db < 2; ++db)
#pragma unroll
    for (int kt = 0; kt < 8; ++kt) {
      short8 w = wov[(db * 8 + kt) * 256 + tid];
      PIN_AGPR(w);
      wf[db][kt] = w;
    }
  __syncthreads();  // xt ready
#pragma unroll
  for (int mt = 0; mt < 2; ++mt) {
    short8 afrag[8];
#pragma unroll
    for (int kt = 0; kt < 8; ++kt)
      afrag[kt] = *(const short8*)&xt[(mt * 16 + lc) * XTS + kt * 32 + lq * 8];
    f32x4 acc[2];
#pragma unroll
    for (int db = 0; db < 2; ++db) {
      acc[db] = (f32x4){0.f, 0.f, 0.f, 0.f};
#pragma unroll
      for (int kt = 0; kt < 8; ++kt)
        acc[db] = __builtin_amdgcn_mfma_f32_16x16x32_bf16(
            afrag[kt], wf[db][kt], acc[db], 0, 0, 0);
    }
#pragma unroll
    for (int db = 0; db < 2; ++db)
#pragma unroll
      for (int r = 0; r < 4; ++r) {
        int m = mt * 16 + lq * 4 + r;
        if (batch * BATCH + m < NN)
          out[nodes_s[m] * 128 + wv * 32 + db * 16 + lc] = acc[db][r];
      }
  }
}

extern "C" void kernel_launch(void* const* d_in, const int* in_sizes, int n_in,
                              void* d_out, int out_size, void* d_ws,
                              size_t ws_size, hipStream_t stream) {
  (void)in_sizes; (void)n_in; (void)out_size; (void)ws_size;
  const float* x     = (const float*)d_in[0];
  const float* W_ih  = (const float*)d_in[1];
  const float* W_hh  = (const float*)d_in[2];
  const float* b_ih  = (const float*)d_in[3];
  const float* b_hh  = (const float*)d_in[4];
  const float* W_out = (const float*)d_in[5];
  const int*   esrc  = (const int*)d_in[6];
  const int*   etrg  = (const int*)d_in[7];
  float* out = (float*)d_out;
  char* ws = (char*)d_ws;

  int*   starts = (int*)(ws + 0);          // 120,000 B
  int*   ends   = (int*)(ws + 120064);     // 120,000 B
  int*   ghist  = (int*)(ws + 240128);     // 196 B (zeroed by memset)
  int*   gclaim = (int*)(ws + 240384);     // 196 B (zeroed by memset)
  int*   order  = (int*)(ws + 240640);     // 120,000 B
  short* proj   = (short*)(ws + 360704);   // 30,720,000 B (bf16, scaled, permuted)
  short* whh_s  = (short*)(ws + 31080704); // 131,072 B (bf16, frag-swizzled, scaled)
  short* wout_s = (short*)(ws + 31211776); // 65,536 B

  (void)hipMemsetAsync(d_ws, 0, 240640, stream);  // starts+ends+ghist+gclaim

  k_prep <<<PREP_EDGE + PREP_WCVT + PREP_PROJ, 256, 0, stream>>>(
      esrc, starts, ends, W_ih, W_hh, W_out, whh_s, wout_s, x, b_ih, b_hh, proj);
  k_hist <<<118, 256, 0, stream>>>(starts, ends, ghist);
  k_scat2<<<118, 256, 0, stream>>>(starts, ends, ghist, gclaim, order);
  k_lstm <<<NB, 256, 0, stream>>>(whh_s, proj, order, starts, ends, etrg,
                                  wout_s, x, out);
}

// Round 9
// 237.534 us; speedup vs baseline: 1.0586x; 1.0586x over previous
//
#include <hip/hip_runtime.h>

#define NN 30000
#define NE 480000
#define NG 512
#define MAXD 48
#define BATCH 32
#define NB 938    // ceil(30000/32)
#define HPAD 144  // h_s row stride in shorts
#define NGB 469   // ceil(30000/64) for the proj GEMM
#define XTS 272   // [x|h] tile row stride in shorts (tail GEMM)

typedef __attribute__((ext_vector_type(8))) short short8;
typedef __attribute__((ext_vector_type(4))) short s16x4;
typedef __attribute__((ext_vector_type(4))) float f32x4;
typedef __attribute__((ext_vector_type(4))) int i32x4;

#define L2E 1.44269504089f   // log2(e)
#define L2E2 2.88539008178f  // 2*log2(e)

static __device__ __forceinline__ short f2bs(float f) {
  unsigned u = __builtin_bit_cast(unsigned, f);
  u = (u + 0x7fffu + ((u >> 16) & 1u)) >> 16;
  return (short)u;
}
// packed f32->bf16 (RNE, same rounding as f2bs): lo = S0, hi = S1.
// Plain-VALU inline asm is safe (hw-interlocked); only MFMA asm was not (r1).
static __device__ __forceinline__ unsigned cvtpk(float lo, float hi) {
  unsigned r;
  asm("v_cvt_pk_bf16_f32 %0, %1, %2" : "=v"(r) : "v"(lo), "v"(hi));
  return r;
}
// async 16B-per-lane gather into LDS: dest = ldsbase + lane*16
static __device__ __forceinline__ void gl_lds16(const short* g, short* l) {
  __builtin_amdgcn_global_load_lds(
      (const __attribute__((address_space(1))) void*)g,
      (__attribute__((address_space(3))) void*)l, 16, 0, 0);
}

// Pin a bf16x8 MFMA B-fragment to AGPRs (gfx950 unified RF: MFMA reads A/B
// from AGPR). Round-3 rocprof verified this kills the arch-VGPR spill:
// k_lstm WRITE_SIZE 107,866 KB -> 7,500 KB. Keep the builtin MFMA
// (compiler-managed hazards); full inline-asm MFMA broke the hazard
// recognizer in round 1 (absmax 0.47).
// r7 lesson: do NOT fuse heavy-register paths with light high-occupancy
// passes — the allocation poisons the light blocks' occupancy (+14 us).
// (r8 never ran: GPU acquisition timeout — infra, not kernel.)
#define PIN_AGPR(w_) asm("" : "+a"(w_))

// ---- prep: segment starts/ends via boundary detection (src sorted) FUSED
// with one-time weight bf16 pre-conversion into per-thread fragment layout
// (LIGHT kernel — no launch-bounds attr, full occupancy; r6-measured good).
// Weights pre-scaled into the exp2 domain (gates i,f,o by log2e, g by
// 2*log2e) so k_lstm uses raw v_exp_f32. W_out NOT scaled. ----
#define EDGE_BLKS 1875
__global__ void k_edges_wcvt(const int* __restrict__ src, int* __restrict__ starts,
                             int* __restrict__ ends,
                             const float* __restrict__ W_ih,
                             const float* __restrict__ W_hh,
                             const float* __restrict__ Wout,
                             short* __restrict__ wih_s, short* __restrict__ whh_s,
                             short* __restrict__ wout_s) {
  const int b = blockIdx.x, tid = threadIdx.x;
  if (b < EDGE_BLKS) {
    int e = b * 256 + tid;
    if (e >= NE) return;
    int s = src[e];
    if (e == 0 || src[e - 1] != s) starts[s] = e;
    if (e == NE - 1 || src[e + 1] != s) ends[s] = e + 1;
    return;
  }
  const int f = b - EDGE_BLKS;  // 0..79
  const int wv = tid >> 6, lq = (tid >> 4) & 3, lc = tid & 15;
  if (f < 64) {
    const float* W = (f < 32) ? W_ih : W_hh;
    short* dst = (f < 32) ? wih_s : whh_s;
    const int ff = f & 31;
    const int g = ff >> 3, db = (ff >> 2) & 1, kt = ff & 3;
    const float s = (g == 2) ? L2E2 : L2E;  // exp2-domain pre-scale
    const float* p = &W[(g * 128 + wv * 32 + db * 16 + lc) * 128 + kt * 32 + lq * 8];
    f32x4 a = *(const f32x4*)p;
    f32x4 c = *(const f32x4*)(p + 4);
    short8 w;
    w[0] = f2bs(a[0] * s); w[1] = f2bs(a[1] * s); w[2] = f2bs(a[2] * s); w[3] = f2bs(a[3] * s);
    w[4] = f2bs(c[0] * s); w[5] = f2bs(c[1] * s); w[6] = f2bs(c[2] * s); w[7] = f2bs(c[3] * s);
    *(short8*)&dst[(ff * 256 + tid) * 8] = w;
  } else {
    const int fo = f - 64;  // 0..15 (W_out: NOT scaled)
    const int db = fo >> 3, kt = fo & 7;
    short8 w;
#pragma unroll
    for (int jj = 0; jj < 8; ++jj)
      w[jj] = f2bs(Wout[(kt * 32 + lq * 8 + jj) * 128 + wv * 32 + db * 16 + lc]);
    *(short8*)&wout_s[(fo * 256 + tid) * 8] = w;
  }
}

// ---- degree histogram (118 blocks; ghist zeroed by launch-side memset).
// Replaces the 1875-block k_nbr_hist: the nbr buffer is GONE (r7-validated:
// k_lstm gathers neighbor ids directly from etrg). ----
__global__ void k_hist(const int* __restrict__ starts, const int* __restrict__ ends,
                       int* __restrict__ ghist) {
  __shared__ int h[MAXD + 1];
  const int tid = threadIdx.x;
  if (tid <= MAXD) h[tid] = 0;
  __syncthreads();
  int n = blockIdx.x * 256 + tid;
  if (n < NN) {
    int c = ends[n] - starts[n]; c = c > MAXD ? MAXD : c;
    atomicAdd(&h[c], 1);
  }
  __syncthreads();
  if (tid <= MAXD && h[tid] > 0) atomicAdd(&ghist[tid], h[tid]);
}

// ---- scatter with inline descending-bucket scan; gclaim[] zeroed by the
// launch-side memset. Within-bucket order arbitrary. ----
__global__ void k_scat2(const int* __restrict__ starts, const int* __restrict__ ends,
                        const int* __restrict__ ghist, int* __restrict__ gclaim,
                        int* __restrict__ order) {
  __shared__ int lh[MAXD + 1];
  __shared__ int lbase[MAXD + 1];
  __shared__ int sbase[MAXD + 1];
  const int tid = threadIdx.x;
  if (tid <= MAXD) lh[tid] = 0;
  __syncthreads();
  int n = blockIdx.x * 256 + tid;
  int c = 0, rank = 0;
  if (n < NN) {
    c = ends[n] - starts[n]; c = c > MAXD ? MAXD : c;
    rank = atomicAdd(&lh[c], 1);
  }
  if (tid == 0) {
    int tot = 0;
    for (int b = MAXD; b >= 0; --b) { sbase[b] = tot; tot += ghist[b]; }
  }
  __syncthreads();
  if (tid <= MAXD && lh[tid] > 0)
    lbase[tid] = sbase[tid] + atomicAdd(&gclaim[tid], lh[tid]);
  __syncthreads();
  if (n < NN) order[lbase[c] + rank] = n;
}

// ---- proj = X @ W_ih.T + (b_ih+b_hh), bf16 MFMA, permuted layout:
// j = g*128 + wv*32 + db*16 + lc  ->  pos = (wv*16+lc)*8 + g*2 + db.
// Weights pre-converted/pre-swizzled (r6-measured good; r7's inline
// conversion regressed). Conversions via v_cvt_pk_bf16_f32. ----
__global__ __launch_bounds__(256)
__attribute__((amdgpu_waves_per_eu(2, 2))) void k_proj(
    const float* __restrict__ x, const short* __restrict__ wih_s,
    const float* __restrict__ b_ih, const float* __restrict__ b_hh,
    short* __restrict__ proj) {
  __shared__ __align__(16) short xs[64 * HPAD];
  const int tid = threadIdx.x;
  const int wv = tid >> 6, lane = tid & 63, lq = lane >> 4, lc = lane & 15;
  const int base = blockIdx.x * 64;

  for (int idx4 = tid; idx4 < 64 * 32; idx4 += 256) {
    int row = idx4 >> 5, k4 = (idx4 & 31) << 2;
    f32x4 v = (f32x4){0.f, 0.f, 0.f, 0.f};
    if (base + row < NN) v = *(const f32x4*)&x[(base + row) * 128 + k4];
    int* xr = (int*)&xs[row * HPAD];
    xr[(k4 >> 1)] = (int)cvtpk(v[0], v[1]);
    xr[(k4 >> 1) + 1] = (int)cvtpk(v[2], v[3]);
  }
  const short8* wihv = (const short8*)wih_s;
  short8 wfrag[4][2][4];
#pragma unroll
  for (int g = 0; g < 4; ++g)
#pragma unroll
    for (int db = 0; db < 2; ++db)
#pragma unroll
      for (int kt = 0; kt < 4; ++kt) {
        short8 w = wihv[(g * 8 + db * 4 + kt) * 256 + tid];
        PIN_AGPR(w);
        wfrag[g][db][kt] = w;
      }
  float bias_v[4][2];
#pragma unroll
  for (int g = 0; g < 4; ++g)
#pragma unroll
    for (int db = 0; db < 2; ++db) {
      int j = g * 128 + wv * 32 + db * 16 + lc;
      bias_v[g][db] = (b_ih[j] + b_hh[j]) * ((g == 2) ? L2E2 : L2E);
    }
  __syncthreads();

#pragma unroll
  for (int mt = 0; mt < 4; ++mt) {
    short8 afrag[4];
#pragma unroll
    for (int kt = 0; kt < 4; ++kt)
      afrag[kt] = *(const short8*)&xs[(mt * 16 + lc) * HPAD + kt * 32 + lq * 8];
    f32x4 acc[4][2];
#pragma unroll
    for (int g = 0; g < 4; ++g)
#pragma unroll
      for (int db = 0; db < 2; ++db) {
        float b = bias_v[g][db];
        acc[g][db] = (f32x4){b, b, b, b};
#pragma unroll
        for (int kt = 0; kt < 4; ++kt)
          acc[g][db] = __builtin_amdgcn_mfma_f32_16x16x32_bf16(
              afrag[kt], wfrag[g][db][kt], acc[g][db], 0, 0, 0);
      }
#pragma unroll
    for (int r = 0; r < 4; ++r) {
      int row = base + mt * 16 + lq * 4 + r;
      if (row < NN) {
        i32x4 w;
        w[0] = (int)cvtpk(acc[0][0][r], acc[0][1][r]);
        w[1] = (int)cvtpk(acc[1][0][r], acc[1][1][r]);
        w[2] = (int)cvtpk(acc[2][0][r], acc[2][1][r]);
        w[3] = (int)cvtpk(acc[3][0][r], acc[3][1][r]);
        *(i32x4*)&proj[row * NG + (wv * 16 + lc) * 8] = w;
      }
    }
  }
}

// ---- LSTM + fused output GEMM. Inner loop unchanged since r5 (W_hh
// AGPR-pinned, exp2-domain gates, distance-1 gl_lds prefetch, one barrier
// per step). Neighbor ids gathered DIRECTLY from etrg (r7-validated; nbr
// buffer eliminated). Tail GEMM (r6): [x|h] staged into dead pbuf, W_out
// frags in the dead wfrag AGPR space. ----
__global__ __launch_bounds__(256)
__attribute__((amdgpu_waves_per_eu(2, 2))) void k_lstm(
    const short* __restrict__ whh_s, const short* __restrict__ proj,
    const int* __restrict__ order, const int* __restrict__ starts,
    const int* __restrict__ ends, const int* __restrict__ etrg,
    const short* __restrict__ wout_s, const float* __restrict__ x,
    float* __restrict__ out) {
  __shared__ __align__(16) short h_s[2][BATCH * HPAD];   // 18432 B
  __shared__ __align__(16) short pbuf[4][8][64 * 8];     // 32768 B, wave-private slots
  __shared__ unsigned short nbr_s[BATCH][MAXD];          // 3072 B
  __shared__ int nodes_s[BATCH];
  __shared__ int cnts_s[BATCH];
  __shared__ int starts_s[BATCH];

  const int tid = threadIdx.x;
  const int wv = tid >> 6, lane = tid & 63, lq = lane >> 4, lc = lane & 15;

  const short8* whhv = (const short8*)whh_s;
  short8 wfrag[4][2][4];
#pragma unroll
  for (int g = 0; g < 4; ++g)
#pragma unroll
    for (int db = 0; db < 2; ++db)
#pragma unroll
      for (int kt = 0; kt < 4; ++kt) {
        short8 w = whhv[(g * 8 + db * 4 + kt) * 256 + tid];
        PIN_AGPR(w);
        wfrag[g][db][kt] = w;
      }

  const int batch = blockIdx.x;
  if (tid < BATCH) {
    int gidx = batch * BATCH + tid;
    int node = 0, c = 0, st = 0;
    if (gidx < NN) {
      node = order[gidx];
      st = starts[node];
      c = ends[node] - st; c = c > MAXD ? MAXD : c;
    }
    nodes_s[tid] = node;
    cnts_s[tid] = c;
    starts_s[tid] = st;
  }
  __syncthreads();
  for (int idx = tid; idx < BATCH * HPAD / 2; idx += 256)
    ((int*)h_s[0])[idx] = 0;
  for (int idx = tid; idx < BATCH * MAXD; idx += 256) {
    int m = idx / MAXD, p = idx - m * MAXD;
    nbr_s[m][p] =
        (p < cnts_s[m]) ? (unsigned short)etrg[starts_s[m] + p] : (unsigned short)0;
  }
  __syncthreads();
  const int T = cnts_s[0];  // descending-bucket grouping -> batch max

  // counts packed 4-per-int (each <= 48 fits in 8 bits)
  int cp[2];
#pragma unroll
  for (int mt = 0; mt < 2; ++mt) {
    int p = 0;
#pragma unroll
    for (int r = 0; r < 4; ++r) p |= cnts_s[mt * 16 + lq * 4 + r] << (r * 8);
    cp[mt] = p;
  }

  float c_v[2][2][4];
  s16x4 hvp[2][2];  // last-written h (bf16) for copy-forward of frozen rows
#pragma unroll
  for (int mt = 0; mt < 2; ++mt)
#pragma unroll
    for (int db = 0; db < 2; ++db) {
#pragma unroll
      for (int r = 0; r < 4; ++r) c_v[mt][db][r] = 0.0f;
      hvp[mt][db] = (s16x4){0, 0, 0, 0};
    }

  const int pcol = (wv * 16 + lc) * 8;
  if (T > 0) {  // prologue: async-gather t=0 slices into pbuf
#pragma unroll
    for (int mt = 0; mt < 2; ++mt)
#pragma unroll
      for (int r = 0; r < 4; ++r) {
        int m = mt * 16 + lq * 4 + r;
        int nb_i = (0 < ((cp[mt] >> (r * 8)) & 255)) ? (int)nbr_s[m][0] : 0;
        gl_lds16(&proj[nb_i * NG + pcol], &pbuf[wv][mt * 4 + r][0]);
      }
  }

  for (int t = 0; t < T; ++t) {
    __syncthreads();  // drains prefetch (vmcnt) + makes h writes visible
    const short* hb = h_s[t & 1];
    short* hw = h_s[(t + 1) & 1];
    const int tn = t + 1;
    const int ts = tn < MAXD ? tn : 0;
#pragma unroll
    for (int mt = 0; mt < 2; ++mt) {
      // consume this step's gathered slices (wave-private slots)
      i32x4 pvi[4];
#pragma unroll
      for (int r = 0; r < 4; ++r)
        pvi[r] = *(const i32x4*)&pbuf[wv][mt * 4 + r][lane * 8];
      f32x4 acc[4][2];
#pragma unroll
      for (int g = 0; g < 4; ++g)
#pragma unroll
        for (int r = 0; r < 4; ++r) {
          unsigned u = (unsigned)pvi[r][g];  // two bf16: db0=lo, db1=hi
          acc[g][0][r] = __builtin_bit_cast(float, u << 16);
          acc[g][1][r] = __builtin_bit_cast(float, u & 0xffff0000u);
        }
      __builtin_amdgcn_sched_barrier(0);  // pvi fully consumed before overwrite
      if (tn < T) {  // prefetch t+1 into the same (now free) slots
#pragma unroll
        for (int r = 0; r < 4; ++r) {
          int m = mt * 16 + lq * 4 + r;
          int nb_i = (tn < ((cp[mt] >> (r * 8)) & 255)) ? (int)nbr_s[m][ts] : 0;
          gl_lds16(&proj[nb_i * NG + pcol], &pbuf[wv][mt * 4 + r][0]);
        }
      }
      __builtin_amdgcn_sched_barrier(0);  // keep prefetch issue early
      short8 afrag[4];
#pragma unroll
      for (int kt = 0; kt < 4; ++kt)
        afrag[kt] = *(const short8*)&hb[(mt * 16 + lc) * HPAD + kt * 32 + lq * 8];
#pragma unroll
      for (int g = 0; g < 4; ++g)
#pragma unroll
        for (int db = 0; db < 2; ++db)
#pragma unroll
          for (int kt = 0; kt < 4; ++kt)
            acc[g][db] = __builtin_amdgcn_mfma_f32_16x16x32_bf16(
                afrag[kt], wfrag[g][db][kt], acc[g][db], 0, 0, 0);
#pragma unroll
      for (int db = 0; db < 2; ++db)
#pragma unroll
        for (int r = 0; r < 4; ++r) {
          float Ei = __builtin_amdgcn_exp2f(-acc[0][db][r]);
          float Eg = __builtin_amdgcn_exp2f(fminf(acc[2][db][r], 125.f));
          float ig = (Eg - 1.f) *
                     __builtin_amdgcn_rcpf((1.f + Ei) * (1.f + Eg));
          float fv = __builtin_amdgcn_rcpf(
              1.f + __builtin_amdgcn_exp2f(-acc[1][db][r]));
          float c2 = fv * c_v[mt][db][r] + ig;
          float Eo = __builtin_amdgcn_exp2f(-acc[3][db][r]);
          float Ec = __builtin_amdgcn_exp2f(fminf(c2 * L2E2, 125.f));
          float h2 = (Ec - 1.f) *
                     __builtin_amdgcn_rcpf((1.f + Eo) * (1.f + Ec));
          if (t < ((cp[mt] >> (r * 8)) & 255)) {
            c_v[mt][db][r] = c2;
            hvp[mt][db][r] = f2bs(h2);
          }
        }
      // unconditional write of (new or carried) h into the other buffer
#pragma unroll
      for (int db = 0; db < 2; ++db)
#pragma unroll
        for (int r = 0; r < 4; ++r)
          hw[(mt * 16 + lq * 4 + r) * HPAD + wv * 32 + db * 16 + lc] =
              hvp[mt][db][r];
    }
  }
  __syncthreads();  // last step's h writes visible; pbuf prefetches drained

  // ---- fused output GEMM: out[32 rows] = [x|h] @ W_out ----
  const short* hf = h_s[T & 1];
  short* xt = (short*)pbuf;  // 32 x XTS(272) shorts = 17408 B, reuses pbuf
  // h half: copy 32x128 bf16 as ints (HPAD-strided -> XTS-strided)
  for (int idx = tid; idx < BATCH * 64; idx += 256) {
    int m = idx >> 6, d2 = idx & 63;
    ((int*)xt)[m * (XTS / 2) + 64 + d2] = ((const int*)&hf[m * HPAD])[d2];
  }
  // x half: gather rows by node id, convert f32->bf16 (cvt_pk)
  for (int idx4 = tid; idx4 < BATCH * 32; idx4 += 256) {
    int m = idx4 >> 5, k4 = (idx4 & 31) << 2;
    f32x4 v = *(const f32x4*)&x[nodes_s[m] * 128 + k4];
    int* xr = (int*)xt + m * (XTS / 2);
    xr[(k4 >> 1)] = (int)cvtpk(v[0], v[1]);
    xr[(k4 >> 1) + 1] = (int)cvtpk(v[2], v[3]);
  }
  // W_out frags into the dead wfrag AGPR space
  const short8* wov = (const short8*)wout_s;
  short8 wf[2][8];
#pragma unroll
  for (int db = 0; db < 2; ++db)
#pragma unroll
    for (int kt = 0; kt < 8; ++kt) {
      short8 w = wov[(db * 8 + kt) * 256 + tid];
      PIN_AGPR(w);
      wf[db][kt] = w;
    }
  __syncthreads();  // xt ready
#pragma unroll
  for (int mt = 0; mt < 2; ++mt) {
    short8 afrag[8];
#pragma unroll
    for (int kt = 0; kt < 8; ++kt)
      afrag[kt] = *(const short8*)&xt[(mt * 16 + lc) * XTS + kt * 32 + lq * 8];
    f32x4 acc[2];
#pragma unroll
    for (int db = 0; db < 2; ++db) {
      acc[db] = (f32x4){0.f, 0.f, 0.f, 0.f};
#pragma unroll
      for (int kt = 0; kt < 8; ++kt)
        acc[db] = __builtin_amdgcn_mfma_f32_16x16x32_bf16(
            afrag[kt], wf[db][kt], acc[db], 0, 0, 0);
    }
#pragma unroll
    for (int db = 0; db < 2; ++db)
#pragma unroll
      for (int r = 0; r < 4; ++r) {
        int m = mt * 16 + lq * 4 + r;
        if (batch * BATCH + m < NN)
          out[nodes_s[m] * 128 + wv * 32 + db * 16 + lc] = acc[db][r];
      }
  }
}

extern "C" void kernel_launch(void* const* d_in, const int* in_sizes, int n_in,
                              void* d_out, int out_size, void* d_ws,
                              size_t ws_size, hipStream_t stream) {
  (void)in_sizes; (void)n_in; (void)out_size; (void)ws_size;
  const float* x     = (const float*)d_in[0];
  const float* W_ih  = (const float*)d_in[1];
  const float* W_hh  = (const float*)d_in[2];
  const float* b_ih  = (const float*)d_in[3];
  const float* b_hh  = (const float*)d_in[4];
  const float* W_out = (const float*)d_in[5];
  const int*   esrc  = (const int*)d_in[6];
  const int*   etrg  = (const int*)d_in[7];
  float* out = (float*)d_out;
  char* ws = (char*)d_ws;

  int*   starts = (int*)(ws + 0);          // 120,000 B
  int*   ends   = (int*)(ws + 120064);     // 120,000 B
  int*   ghist  = (int*)(ws + 240128);     // 196 B (zeroed by memset)
  int*   gclaim = (int*)(ws + 240384);     // 196 B (zeroed by memset)
  int*   order  = (int*)(ws + 240640);     // 120,000 B
  short* proj   = (short*)(ws + 360704);   // 30,720,000 B (bf16, scaled, permuted)
  short* wih_s  = (short*)(ws + 31080704); // 131,072 B (bf16, frag-swizzled, scaled)
  short* whh_s  = (short*)(ws + 31211776); // 131,072 B
  short* wout_s = (short*)(ws + 31342848); // 65,536 B

  (void)hipMemsetAsync(d_ws, 0, 240640, stream);  // starts+ends+ghist+gclaim

  k_edges_wcvt<<<EDGE_BLKS + 80, 256, 0, stream>>>(esrc, starts, ends, W_ih,
                                                   W_hh, W_out, wih_s, whh_s,
                                                   wout_s);
  k_hist <<<118, 256, 0, stream>>>(starts, ends, ghist);
  k_scat2<<<118, 256, 0, stream>>>(starts, ends, ghist, gclaim, order);
  k_proj <<<NGB, 256, 0, stream>>>(x, wih_s, b_ih, b_hh, proj);
  k_lstm <<<NB, 256, 0, stream>>>(whh_s, proj, order, starts, ends, etrg,
                                  wout_s, x, out);
}